// Round 1
// baseline (4279.045 us; speedup 1.0000x reference)
//
#include <hip/hip_runtime.h>
#include <hip/hip_bf16.h>
#include <math.h>

#define C_DIM 1024
#define H_DIM 4096
#define E_NUM 8

// ---------------------------------------------------------------------------
// Router: per-token block. logits = x@Wr, noise_logits = x@Wn,
// noisy = logits + noise * softplus(noise_logits), top-2 (ties -> lower idx),
// gates = softmax over the two kept entries.
// ---------------------------------------------------------------------------
__global__ __launch_bounds__(256) void router_kernel(
    const float* __restrict__ x, const float* __restrict__ noise,
    const float* __restrict__ Wr, const float* __restrict__ Wn,
    int2* __restrict__ idx_out, float2* __restrict__ gate_out, int N)
{
  int t = blockIdx.x;
  int tid = threadIdx.x;
  const float* xrow = x + (size_t)t * C_DIM;
  float accR[E_NUM], accN[E_NUM];
#pragma unroll
  for (int e = 0; e < E_NUM; e++) { accR[e] = 0.f; accN[e] = 0.f; }
  for (int c = tid; c < C_DIM; c += 256) {
    float xv = xrow[c];
    const float* wr = Wr + (size_t)c * E_NUM;
    const float* wn = Wn + (size_t)c * E_NUM;
#pragma unroll
    for (int e = 0; e < E_NUM; e++) {
      accR[e] = fmaf(xv, wr[e], accR[e]);
      accN[e] = fmaf(xv, wn[e], accN[e]);
    }
  }
  // 64-lane wave reduce, then cross-wave via LDS
#pragma unroll
  for (int e = 0; e < E_NUM; e++) {
    for (int off = 32; off > 0; off >>= 1) {
      accR[e] += __shfl_down(accR[e], off, 64);
      accN[e] += __shfl_down(accN[e], off, 64);
    }
  }
  __shared__ float red[4][2 * E_NUM];
  int lane = tid & 63, wave = tid >> 6;
  if (lane == 0) {
#pragma unroll
    for (int e = 0; e < E_NUM; e++) { red[wave][e] = accR[e]; red[wave][E_NUM + e] = accN[e]; }
  }
  __syncthreads();
  if (tid == 0) {
    float ns[E_NUM];
#pragma unroll
    for (int e = 0; e < E_NUM; e++) {
      float lg = red[0][e] + red[1][e] + red[2][e] + red[3][e];
      float nl = red[0][E_NUM + e] + red[1][E_NUM + e] + red[2][E_NUM + e] + red[3][E_NUM + e];
      // softplus(z) = max(z,0) + log1p(exp(-|z|))  (jax-stable form)
      float sp = fmaxf(nl, 0.f) + log1pf(expf(-fabsf(nl)));
      ns[e] = lg + noise[(size_t)t * E_NUM + e] * sp;
    }
    // top-2, strict > keeps lowest index on ties (matches jax.lax.top_k)
    int i1 = 0; float m1 = ns[0];
    int i2 = -1; float m2 = -INFINITY;
#pragma unroll
    for (int e = 1; e < E_NUM; e++) {
      float v = ns[e];
      if (v > m1) { m2 = m1; i2 = i1; m1 = v; i1 = e; }
      else if (v > m2) { m2 = v; i2 = e; }
    }
    float e2 = expf(m2 - m1);
    float s = 1.f + e2;
    gate_out[t] = make_float2(1.f / s, e2 / s);
    idx_out[t] = make_int2(i1, i2);
  }
}

// ---------------------------------------------------------------------------
// Capacity scan: one block per expert, stable token-order prefix sum.
// s2t[e][slot] = token (or N for pad), gslot[e][slot] = gating weight.
// ---------------------------------------------------------------------------
__global__ __launch_bounds__(256) void scan_kernel(
    const int2* __restrict__ idx, const float2* __restrict__ gates,
    int* __restrict__ s2t, float* __restrict__ gslot, int N, int cap)
{
  int e = blockIdx.x;
  int tid = threadIdx.x;
  for (int s = tid; s < cap; s += 256) { s2t[(size_t)e * cap + s] = N; gslot[(size_t)e * cap + s] = 0.f; }
  __syncthreads();
  __shared__ int wtot[4];
  int lane = tid & 63, wave = tid >> 6;
  int running = 0;
  for (int base = 0; base < N; base += 256) {
    int t = base + tid;   // N is a multiple of 256
    int2 ix = idx[t];
    bool flag = (ix.x == e) || (ix.y == e);
    unsigned long long m = __ballot(flag);
    int rank = __popcll(m & ((1ull << lane) - 1ull));
    if (lane == 0) wtot[wave] = __popcll(m);
    __syncthreads();
    int woff = 0;
    for (int w = 0; w < wave; w++) woff += wtot[w];
    int slot = running + woff + rank;
    if (flag && slot < cap) {
      s2t[(size_t)e * cap + slot] = t;
      gslot[(size_t)e * cap + slot] = (ix.x == e) ? gates[t].x : gates[t].y;
    }
    running += wtot[0] + wtot[1] + wtot[2] + wtot[3];
    __syncthreads();
  }
}

// ---------------------------------------------------------------------------
// Expert MLP layer 1: h[slot] = silu(x[s2t[e][slot]] @ W1[e])  (M=cap,K=1024,N=4096)
// 64x64 tile, 256 threads, 4x4 microtile. f32 (correctness round).
// ---------------------------------------------------------------------------
#define BM 64
#define BN 64
#define BK 16

__global__ __launch_bounds__(256) void mlp1_kernel(
    const float* __restrict__ x, const float* __restrict__ W1,
    const int* __restrict__ s2t, float* __restrict__ h,
    int eBase, int cap, int N)
{
  int ez = blockIdx.z;
  int e = eBase + ez;
  const float* Bw = W1 + (size_t)e * C_DIM * H_DIM;
  float* hE = h + (size_t)ez * (size_t)cap * H_DIM;
  int row0 = blockIdx.y * BM;
  int col0 = blockIdx.x * BN;
  int tid = threadIdx.x;
  int tx = tid & 15, ty = tid >> 4;
  int arow = tid >> 2, aq = tid & 3;
  int tok = s2t[(size_t)e * cap + row0 + arow];
  const float* aptr = (tok < N) ? (x + (size_t)tok * C_DIM + aq * 4) : nullptr;

  __shared__ float As[BK][BM + 4];
  __shared__ float Bs[BK][BN];

  float acc[4][4];
#pragma unroll
  for (int i = 0; i < 4; i++)
#pragma unroll
    for (int j = 0; j < 4; j++) acc[i][j] = 0.f;

  for (int k0 = 0; k0 < C_DIM; k0 += BK) {
    float4 av = make_float4(0.f, 0.f, 0.f, 0.f);
    if (aptr) av = *(const float4*)(aptr + k0);
    As[aq * 4 + 0][arow] = av.x;
    As[aq * 4 + 1][arow] = av.y;
    As[aq * 4 + 2][arow] = av.z;
    As[aq * 4 + 3][arow] = av.w;
    float4 bv = *(const float4*)(Bw + (size_t)(k0 + ty) * H_DIM + col0 + tx * 4);
    *(float4*)&Bs[ty][tx * 4] = bv;
    __syncthreads();
#pragma unroll
    for (int k = 0; k < BK; k++) {
      float a[4], b[4];
#pragma unroll
      for (int i = 0; i < 4; i++) a[i] = As[k][ty * 4 + i];
#pragma unroll
      for (int j = 0; j < 4; j++) b[j] = Bs[k][tx * 4 + j];
#pragma unroll
      for (int i = 0; i < 4; i++)
#pragma unroll
        for (int j = 0; j < 4; j++) acc[i][j] = fmaf(a[i], b[j], acc[i][j]);
    }
    __syncthreads();
  }
#pragma unroll
  for (int i = 0; i < 4; i++) {
    int r = row0 + ty * 4 + i;
    float4 o;
    float v;
    v = acc[i][0]; o.x = v / (1.f + expf(-v));
    v = acc[i][1]; o.y = v / (1.f + expf(-v));
    v = acc[i][2]; o.z = v / (1.f + expf(-v));
    v = acc[i][3]; o.w = v / (1.f + expf(-v));
    *(float4*)(hE + (size_t)r * H_DIM + col0 + tx * 4) = o;
  }
}

// ---------------------------------------------------------------------------
// Expert MLP layer 2: out[tok] += gate * (h[slot] @ W2[e])  (M=cap,K=4096,N=1024)
// ---------------------------------------------------------------------------
__global__ __launch_bounds__(256) void mlp2_kernel(
    const float* __restrict__ h, const float* __restrict__ W2,
    const int* __restrict__ s2t, const float* __restrict__ gslot,
    float* __restrict__ out, int eBase, int cap, int N, int useAtomic)
{
  int ez = blockIdx.z;
  int e = eBase + ez;
  const float* A = h + (size_t)ez * (size_t)cap * H_DIM;
  const float* Bw = W2 + (size_t)e * H_DIM * C_DIM;
  int row0 = blockIdx.y * BM;
  int col0 = blockIdx.x * BN;
  int tid = threadIdx.x;
  int tx = tid & 15, ty = tid >> 4;
  int arow = tid >> 2, aq = tid & 3;
  const float* aptr = A + (size_t)(row0 + arow) * H_DIM + aq * 4;

  __shared__ float As[BK][BM + 4];
  __shared__ float Bs[BK][BN];

  float acc[4][4];
#pragma unroll
  for (int i = 0; i < 4; i++)
#pragma unroll
    for (int j = 0; j < 4; j++) acc[i][j] = 0.f;

  for (int k0 = 0; k0 < H_DIM; k0 += BK) {
    float4 av = *(const float4*)(aptr + k0);
    As[aq * 4 + 0][arow] = av.x;
    As[aq * 4 + 1][arow] = av.y;
    As[aq * 4 + 2][arow] = av.z;
    As[aq * 4 + 3][arow] = av.w;
    float4 bv = *(const float4*)(Bw + (size_t)(k0 + ty) * C_DIM + col0 + tx * 4);
    *(float4*)&Bs[ty][tx * 4] = bv;
    __syncthreads();
#pragma unroll
    for (int k = 0; k < BK; k++) {
      float a[4], b[4];
#pragma unroll
      for (int i = 0; i < 4; i++) a[i] = As[k][ty * 4 + i];
#pragma unroll
      for (int j = 0; j < 4; j++) b[j] = Bs[k][tx * 4 + j];
#pragma unroll
      for (int i = 0; i < 4; i++)
#pragma unroll
        for (int j = 0; j < 4; j++) acc[i][j] = fmaf(a[i], b[j], acc[i][j]);
    }
    __syncthreads();
  }
#pragma unroll
  for (int i = 0; i < 4; i++) {
    int slot = row0 + ty * 4 + i;
    int tok = s2t[(size_t)e * cap + slot];
    if (tok < N) {
      float g = gslot[(size_t)e * cap + slot];
      float* op = out + (size_t)tok * C_DIM + col0 + tx * 4;
      if (useAtomic) {
        atomicAdd(op + 0, g * acc[i][0]);
        atomicAdd(op + 1, g * acc[i][1]);
        atomicAdd(op + 2, g * acc[i][2]);
        atomicAdd(op + 3, g * acc[i][3]);
      } else {
        op[0] += g * acc[i][0];
        op[1] += g * acc[i][1];
        op[2] += g * acc[i][2];
        op[3] += g * acc[i][3];
      }
    }
  }
}

extern "C" void kernel_launch(void* const* d_in, const int* in_sizes, int n_in,
                              void* d_out, int out_size, void* d_ws, size_t ws_size,
                              hipStream_t stream)
{
  const float* x     = (const float*)d_in[0];
  const float* noise = (const float*)d_in[1];
  const float* Wr    = (const float*)d_in[2];
  const float* Wn    = (const float*)d_in[3];
  const float* W1    = (const float*)d_in[4];
  const float* W2    = (const float*)d_in[5];
  float* out = (float*)d_out;

  int N = in_sizes[0] / C_DIM;                       // 8192
  int cap = (int)((double)N * 2.0 / E_NUM * 1.25);   // 2560

  char* p = (char*)d_ws;
  auto alloc = [&](size_t bytes) -> char* {
    char* r = p;
    p += (bytes + 255) & ~(size_t)255;
    return r;
  };
  int2*   idx   = (int2*)alloc((size_t)N * sizeof(int2));
  float2* gates = (float2*)alloc((size_t)N * sizeof(float2));
  int*    s2t   = (int*)alloc((size_t)E_NUM * cap * sizeof(int));
  float*  gslot = (float*)alloc((size_t)E_NUM * cap * sizeof(float));
  float*  h     = (float*)p;
  size_t used = (size_t)(p - (char*)d_ws);
  size_t hPer = (size_t)cap * H_DIM * sizeof(float);
  bool fused = ws_size >= used + (size_t)E_NUM * hPer;

  hipMemsetAsync(d_out, 0, (size_t)out_size * sizeof(float), stream);
  router_kernel<<<N, 256, 0, stream>>>(x, noise, Wr, Wn, idx, gates, N);
  scan_kernel<<<E_NUM, 256, 0, stream>>>(idx, gates, s2t, gslot, N, cap);

  if (fused) {
    mlp1_kernel<<<dim3(H_DIM / BN, cap / BM, E_NUM), 256, 0, stream>>>(x, W1, s2t, h, 0, cap, N);
    mlp2_kernel<<<dim3(C_DIM / BN, cap / BM, E_NUM), 256, 0, stream>>>(h, W2, s2t, gslot, out, 0, cap, N, 1);
  } else {
    for (int e = 0; e < E_NUM; e++) {
      mlp1_kernel<<<dim3(H_DIM / BN, cap / BM, 1), 256, 0, stream>>>(x, W1, s2t, h, e, cap, N);
      mlp2_kernel<<<dim3(C_DIM / BN, cap / BM, 1), 256, 0, stream>>>(h, W2, s2t, gslot, out, e, cap, N, 0);
    }
  }
}

// Round 2
// 903.521 us; speedup vs baseline: 4.7360x; 4.7360x over previous
//
#include <hip/hip_runtime.h>
#include <hip/hip_bf16.h>
#include <math.h>

#define C_DIM 1024
#define H_DIM 4096
#define E_NUM 8

typedef __bf16 bf16x8 __attribute__((ext_vector_type(8)));
typedef float f32x4 __attribute__((ext_vector_type(4)));

__device__ __forceinline__ unsigned short f2bf(float f) {
  union { float f; unsigned u; } v; v.f = f;
  unsigned r = v.u + 0x7FFFu + ((v.u >> 16) & 1u);   // round-to-nearest-even
  return (unsigned short)(r >> 16);
}

__device__ __forceinline__ void gload16(const short* g, short* l) {
  __builtin_amdgcn_global_load_lds(
      (const __attribute__((address_space(1))) unsigned int*)g,
      (__attribute__((address_space(3))) unsigned int*)l, 16, 0, 0);
}

// ---------------------------------------------------------------------------
// Router (validated round 1)
// ---------------------------------------------------------------------------
__global__ __launch_bounds__(256) void router_kernel(
    const float* __restrict__ x, const float* __restrict__ noise,
    const float* __restrict__ Wr, const float* __restrict__ Wn,
    int2* __restrict__ idx_out, float2* __restrict__ gate_out, int N)
{
  int t = blockIdx.x;
  int tid = threadIdx.x;
  const float* xrow = x + (size_t)t * C_DIM;
  float accR[E_NUM], accN[E_NUM];
#pragma unroll
  for (int e = 0; e < E_NUM; e++) { accR[e] = 0.f; accN[e] = 0.f; }
  for (int c = tid; c < C_DIM; c += 256) {
    float xv = xrow[c];
    const float* wr = Wr + (size_t)c * E_NUM;
    const float* wn = Wn + (size_t)c * E_NUM;
#pragma unroll
    for (int e = 0; e < E_NUM; e++) {
      accR[e] = fmaf(xv, wr[e], accR[e]);
      accN[e] = fmaf(xv, wn[e], accN[e]);
    }
  }
#pragma unroll
  for (int e = 0; e < E_NUM; e++) {
    for (int off = 32; off > 0; off >>= 1) {
      accR[e] += __shfl_down(accR[e], off, 64);
      accN[e] += __shfl_down(accN[e], off, 64);
    }
  }
  __shared__ float red[4][2 * E_NUM];
  int lane = tid & 63, wave = tid >> 6;
  if (lane == 0) {
#pragma unroll
    for (int e = 0; e < E_NUM; e++) { red[wave][e] = accR[e]; red[wave][E_NUM + e] = accN[e]; }
  }
  __syncthreads();
  if (tid == 0) {
    float ns[E_NUM];
#pragma unroll
    for (int e = 0; e < E_NUM; e++) {
      float lg = red[0][e] + red[1][e] + red[2][e] + red[3][e];
      float nl = red[0][E_NUM + e] + red[1][E_NUM + e] + red[2][E_NUM + e] + red[3][E_NUM + e];
      float sp = fmaxf(nl, 0.f) + log1pf(expf(-fabsf(nl)));
      ns[e] = lg + noise[(size_t)t * E_NUM + e] * sp;
    }
    int i1 = 0; float m1 = ns[0];
    int i2 = -1; float m2 = -INFINITY;
#pragma unroll
    for (int e = 1; e < E_NUM; e++) {
      float v = ns[e];
      if (v > m1) { m2 = m1; i2 = i1; m1 = v; i1 = e; }
      else if (v > m2) { m2 = v; i2 = e; }
    }
    float e2 = expf(m2 - m1);
    float s = 1.f + e2;
    gate_out[t] = make_float2(1.f / s, e2 / s);
    idx_out[t] = make_int2(i1, i2);
  }
}

// ---------------------------------------------------------------------------
// Capacity scan (validated round 1)
// ---------------------------------------------------------------------------
__global__ __launch_bounds__(256) void scan_kernel(
    const int2* __restrict__ idx, const float2* __restrict__ gates,
    int* __restrict__ s2t, float* __restrict__ gslot, int N, int cap)
{
  int e = blockIdx.x;
  int tid = threadIdx.x;
  for (int s = tid; s < cap; s += 256) { s2t[(size_t)e * cap + s] = N; gslot[(size_t)e * cap + s] = 0.f; }
  __syncthreads();
  __shared__ int wtot[4];
  int lane = tid & 63, wave = tid >> 6;
  int running = 0;
  for (int base = 0; base < N; base += 256) {
    int t = base + tid;
    int2 ix = idx[t];
    bool flag = (ix.x == e) || (ix.y == e);
    unsigned long long m = __ballot(flag);
    int rank = __popcll(m & ((1ull << lane) - 1ull));
    if (lane == 0) wtot[wave] = __popcll(m);
    __syncthreads();
    int woff = 0;
    for (int w = 0; w < wave; w++) woff += wtot[w];
    int slot = running + woff + rank;
    if (flag && slot < cap) {
      s2t[(size_t)e * cap + slot] = t;
      gslot[(size_t)e * cap + slot] = (ix.x == e) ? gates[t].x : gates[t].y;
    }
    running += wtot[0] + wtot[1] + wtot[2] + wtot[3];
    __syncthreads();
  }
}

// ---------------------------------------------------------------------------
// f32 -> bf16, 8 elems/thread
// ---------------------------------------------------------------------------
__global__ __launch_bounds__(256) void convert_x_kernel(
    const float* __restrict__ src, short* __restrict__ dst, int n8)
{
  int i = blockIdx.x * 256 + threadIdx.x;
  if (i >= n8) return;
  const float4* s = (const float4*)src + (size_t)i * 2;
  float4 a = s[0], b = s[1];
  union { unsigned short us[8]; uint4 v; } o;
  o.us[0] = f2bf(a.x); o.us[1] = f2bf(a.y); o.us[2] = f2bf(a.z); o.us[3] = f2bf(a.w);
  o.us[4] = f2bf(b.x); o.us[5] = f2bf(b.y); o.us[6] = f2bf(b.z); o.us[7] = f2bf(b.w);
  ((uint4*)dst)[i] = o.v;
}

// ---------------------------------------------------------------------------
// f32 [R][Cc] -> bf16 [Cc][R]  (64x64 LDS tile transpose + convert)
// ---------------------------------------------------------------------------
__global__ __launch_bounds__(256) void transpose_convert_kernel(
    const float* __restrict__ src, short* __restrict__ dst,
    int R, int Cc, int eBase)
{
  src += (size_t)(eBase + blockIdx.z) * R * Cc;
  dst += (size_t)blockIdx.z * (size_t)R * Cc;
  __shared__ float tile[64][65];
  int c0 = blockIdx.x * 64, r0 = blockIdx.y * 64;
  int tid = threadIdx.x;
  int tr = tid >> 4, tc = (tid & 15) * 4;
#pragma unroll
  for (int p = 0; p < 4; p++) {
    int r = p * 16 + tr;
    float4 v = *(const float4*)(src + (size_t)(r0 + r) * Cc + c0 + tc);
    tile[r][tc] = v.x; tile[r][tc + 1] = v.y; tile[r][tc + 2] = v.z; tile[r][tc + 3] = v.w;
  }
  __syncthreads();
#pragma unroll
  for (int p = 0; p < 4; p++) {
    int c = p * 16 + tr;
    union { unsigned short us[4]; ushort4 v; } o;
#pragma unroll
    for (int j = 0; j < 4; j++) o.us[j] = f2bf(tile[tc + j][c]);
    *(ushort4*)(dst + (size_t)(c0 + c) * R + r0 + tc) = o.v;
  }
}

// ---------------------------------------------------------------------------
// MFMA GEMM, m97 structure: 128x128 tile, BK=32, 4 waves (2x2), 16 MFMA/K-step.
// LDS k-block layout [4][128][8] bf16: linear for global_load_lds, b128 frag reads.
// mlp1: h[slot][:] = silu(x[s2t[slot]] @ W1t^T), h stored bf16 [cap][H]
// ---------------------------------------------------------------------------
__global__ __launch_bounds__(256) void mlp1_kernel(
    const short* __restrict__ xbf, const short* __restrict__ W1t,
    const int* __restrict__ s2t, short* __restrict__ h,
    int eBase, int cap, int N)
{
  int ez = blockIdx.z;
  int e = eBase + ez;
  const short* Wt = W1t + (size_t)ez * C_DIM * H_DIM;          // [H][C]
  short* hE = h + (size_t)ez * (size_t)cap * H_DIM;
  int row0 = blockIdx.y * 128;
  int col0 = blockIdx.x * 128;
  int tid = threadIdx.x;
  int w = tid >> 6, lane = tid & 63;

  __shared__ short As[4096];   // [kb=4][128 rows][8]
  __shared__ short Bs[4096];

  int tokA = min(s2t[(size_t)e * cap + row0 + lane], N - 1);
  int tokB = min(s2t[(size_t)e * cap + row0 + 64 + lane], N - 1);
  const short* pA0 = xbf + (size_t)tokA * C_DIM + w * 8;
  const short* pA1 = xbf + (size_t)tokB * C_DIM + w * 8;
  const short* pB0 = Wt + (size_t)(col0 + lane) * C_DIM + w * 8;
  const short* pB1 = Wt + (size_t)(col0 + 64 + lane) * C_DIM + w * 8;
  short* lA0 = &As[w * 1024];
  short* lA1 = &As[w * 1024 + 512];
  short* lB0 = &Bs[w * 1024];
  short* lB1 = &Bs[w * 1024 + 512];

  int wr = w >> 1, wc = w & 1;
  int fr = lane & 15, fb = lane >> 4;
  int aoff = (fb * 128 + wr * 64 + fr) * 8;
  int boff = (fb * 128 + wc * 64 + fr) * 8;

  f32x4 acc[4][4];
#pragma unroll
  for (int m = 0; m < 4; m++)
#pragma unroll
    for (int n = 0; n < 4; n++) acc[m][n] = 0.f;

  for (int k0 = 0; k0 < C_DIM; k0 += 32) {
    gload16(pA0 + k0, lA0);
    gload16(pA1 + k0, lA1);
    gload16(pB0 + k0, lB0);
    gload16(pB1 + k0, lB1);
    __syncthreads();
    bf16x8 af[4], bg[4];
#pragma unroll
    for (int m = 0; m < 4; m++) af[m] = *(const bf16x8*)&As[aoff + m * 128];
#pragma unroll
    for (int n = 0; n < 4; n++) bg[n] = *(const bf16x8*)&Bs[boff + n * 128];
#pragma unroll
    for (int m = 0; m < 4; m++)
#pragma unroll
      for (int n = 0; n < 4; n++)
        acc[m][n] = __builtin_amdgcn_mfma_f32_16x16x32_bf16(af[m], bg[n], acc[m][n], 0, 0, 0);
    __syncthreads();
  }
  int orow = row0 + wr * 64 + fb * 4;
  int ocol = col0 + wc * 64 + fr;
#pragma unroll
  for (int m = 0; m < 4; m++)
#pragma unroll
    for (int r = 0; r < 4; r++) {
      size_t rbase = (size_t)(orow + m * 16 + r) * H_DIM + ocol;
#pragma unroll
      for (int n = 0; n < 4; n++) {
        float v = acc[m][n][r];
        hE[rbase + n * 16] = (short)f2bf(v / (1.f + expf(-v)));
      }
    }
}

// ---------------------------------------------------------------------------
// mlp2: out[tok] += gate * (h[slot] @ W2t^T)   (atomics, f32)
// ---------------------------------------------------------------------------
__global__ __launch_bounds__(256) void mlp2_kernel(
    const short* __restrict__ h, const short* __restrict__ W2t,
    const int* __restrict__ s2t, const float* __restrict__ gslot,
    float* __restrict__ out, int eBase, int cap, int N)
{
  int ez = blockIdx.z;
  int e = eBase + ez;
  const short* A = h + (size_t)ez * (size_t)cap * H_DIM;       // [cap][H]
  const short* Wt = W2t + (size_t)ez * C_DIM * H_DIM;          // [C][H]
  int row0 = blockIdx.y * 128;
  int col0 = blockIdx.x * 128;
  int tid = threadIdx.x;
  int w = tid >> 6, lane = tid & 63;

  __shared__ short As[4096];
  __shared__ short Bs[4096];

  const short* pA0 = A + (size_t)(row0 + lane) * H_DIM + w * 8;
  const short* pA1 = A + (size_t)(row0 + 64 + lane) * H_DIM + w * 8;
  const short* pB0 = Wt + (size_t)(col0 + lane) * H_DIM + w * 8;
  const short* pB1 = Wt + (size_t)(col0 + 64 + lane) * H_DIM + w * 8;
  short* lA0 = &As[w * 1024];
  short* lA1 = &As[w * 1024 + 512];
  short* lB0 = &Bs[w * 1024];
  short* lB1 = &Bs[w * 1024 + 512];

  int wr = w >> 1, wc = w & 1;
  int fr = lane & 15, fb = lane >> 4;
  int aoff = (fb * 128 + wr * 64 + fr) * 8;
  int boff = (fb * 128 + wc * 64 + fr) * 8;

  f32x4 acc[4][4];
#pragma unroll
  for (int m = 0; m < 4; m++)
#pragma unroll
    for (int n = 0; n < 4; n++) acc[m][n] = 0.f;

  for (int k0 = 0; k0 < H_DIM; k0 += 32) {
    gload16(pA0 + k0, lA0);
    gload16(pA1 + k0, lA1);
    gload16(pB0 + k0, lB0);
    gload16(pB1 + k0, lB1);
    __syncthreads();
    bf16x8 af[4], bg[4];
#pragma unroll
    for (int m = 0; m < 4; m++) af[m] = *(const bf16x8*)&As[aoff + m * 128];
#pragma unroll
    for (int n = 0; n < 4; n++) bg[n] = *(const bf16x8*)&Bs[boff + n * 128];
#pragma unroll
    for (int m = 0; m < 4; m++)
#pragma unroll
      for (int n = 0; n < 4; n++)
        acc[m][n] = __builtin_amdgcn_mfma_f32_16x16x32_bf16(af[m], bg[n], acc[m][n], 0, 0, 0);
    __syncthreads();
  }
  int ocol = col0 + wc * 64 + fr;
#pragma unroll
  for (int m = 0; m < 4; m++)
#pragma unroll
    for (int r = 0; r < 4; r++) {
      int slot = row0 + wr * 64 + m * 16 + fb * 4 + r;
      int tok = s2t[(size_t)e * cap + slot];
      if (tok < N) {
        float g = gslot[(size_t)e * cap + slot];
        float* op = out + (size_t)tok * C_DIM + ocol;
#pragma unroll
        for (int n = 0; n < 4; n++)
          atomicAdd(op + n * 16, g * acc[m][n][r]);
      }
    }
}

extern "C" void kernel_launch(void* const* d_in, const int* in_sizes, int n_in,
                              void* d_out, int out_size, void* d_ws, size_t ws_size,
                              hipStream_t stream)
{
  const float* x     = (const float*)d_in[0];
  const float* noise = (const float*)d_in[1];
  const float* Wr    = (const float*)d_in[2];
  const float* Wn    = (const float*)d_in[3];
  const float* W1    = (const float*)d_in[4];
  const float* W2    = (const float*)d_in[5];
  float* out = (float*)d_out;

  int N = in_sizes[0] / C_DIM;                        // 8192
  int cap = (int)((double)N * 2.0 / E_NUM * 1.25);    // 2560

  size_t off = 0;
  auto alloc = [&](size_t bytes) -> char* {
    char* r = (char*)d_ws + off;
    off += (bytes + 255) & ~(size_t)255;
    return r;
  };
  int2*   idx   = (int2*)alloc((size_t)N * sizeof(int2));
  float2* gates = (float2*)alloc((size_t)N * sizeof(float2));
  int*    s2t   = (int*)alloc((size_t)E_NUM * cap * sizeof(int));
  float*  gslot = (float*)alloc((size_t)E_NUM * cap * sizeof(float));
  short*  xbf   = (short*)alloc((size_t)N * C_DIM * sizeof(short));
  size_t fixed = off;

  size_t wBytes = (size_t)C_DIM * H_DIM * sizeof(short);       // 8 MB
  size_t hBytes = (size_t)cap * H_DIM * sizeof(short);         // 21 MB
  size_t perE = 2 * ((wBytes + 255) & ~(size_t)255) + ((hBytes + 255) & ~(size_t)255);
  int g = (ws_size > fixed) ? (int)((ws_size - fixed) / perE) : 1;
  if (g < 1) g = 1;
  if (g > E_NUM) g = E_NUM;
  short* W1t = (short*)alloc((size_t)g * wBytes);
  short* W2t = (short*)alloc((size_t)g * wBytes);
  short* h   = (short*)alloc((size_t)g * hBytes);

  hipMemsetAsync(d_out, 0, (size_t)out_size * sizeof(float), stream);
  router_kernel<<<N, 256, 0, stream>>>(x, noise, Wr, Wn, idx, gates, N);
  scan_kernel<<<E_NUM, 256, 0, stream>>>(idx, gates, s2t, gslot, N, cap);
  convert_x_kernel<<<(N * C_DIM / 8 + 255) / 256, 256, 0, stream>>>(x, xbf, N * C_DIM / 8);

  for (int eb = 0; eb < E_NUM; eb += g) {
    int ge = min(g, E_NUM - eb);
    transpose_convert_kernel<<<dim3(H_DIM / 64, C_DIM / 64, ge), 256, 0, stream>>>(
        W1, W1t, C_DIM, H_DIM, eb);
    transpose_convert_kernel<<<dim3(C_DIM / 64, H_DIM / 64, ge), 256, 0, stream>>>(
        W2, W2t, H_DIM, C_DIM, eb);
    mlp1_kernel<<<dim3(H_DIM / 128, cap / 128, ge), 256, 0, stream>>>(
        xbf, W1t, s2t, h, eb, cap, N);
    mlp2_kernel<<<dim3(C_DIM / 128, cap / 128, ge), 256, 0, stream>>>(
        h, W2t, s2t, gslot, out, eb, cap, N);
  }
}

// Round 3
// 865.674 us; speedup vs baseline: 4.9430x; 1.0437x over previous
//
#include <hip/hip_runtime.h>
#include <hip/hip_bf16.h>
#include <math.h>

#define C_DIM 1024
#define H_DIM 4096
#define E_NUM 8

typedef __bf16 bf16x8 __attribute__((ext_vector_type(8)));
typedef float f32x4 __attribute__((ext_vector_type(4)));

__device__ __forceinline__ unsigned short f2bf(float f) {
  union { float f; unsigned u; } v; v.f = f;
  unsigned r = v.u + 0x7FFFu + ((v.u >> 16) & 1u);   // round-to-nearest-even
  return (unsigned short)(r >> 16);
}

__device__ __forceinline__ void gload16(const short* g, short* l) {
  __builtin_amdgcn_global_load_lds(
      (const __attribute__((address_space(1))) unsigned int*)g,
      (__attribute__((address_space(3))) unsigned int*)l, 16, 0, 0);
}

// ---------------------------------------------------------------------------
// Router (validated rounds 1-2)
// ---------------------------------------------------------------------------
__global__ __launch_bounds__(256) void router_kernel(
    const float* __restrict__ x, const float* __restrict__ noise,
    const float* __restrict__ Wr, const float* __restrict__ Wn,
    int2* __restrict__ idx_out, float2* __restrict__ gate_out, int N)
{
  int t = blockIdx.x;
  int tid = threadIdx.x;
  const float* xrow = x + (size_t)t * C_DIM;
  float accR[E_NUM], accN[E_NUM];
#pragma unroll
  for (int e = 0; e < E_NUM; e++) { accR[e] = 0.f; accN[e] = 0.f; }
  for (int c = tid; c < C_DIM; c += 256) {
    float xv = xrow[c];
    const float* wr = Wr + (size_t)c * E_NUM;
    const float* wn = Wn + (size_t)c * E_NUM;
#pragma unroll
    for (int e = 0; e < E_NUM; e++) {
      accR[e] = fmaf(xv, wr[e], accR[e]);
      accN[e] = fmaf(xv, wn[e], accN[e]);
    }
  }
#pragma unroll
  for (int e = 0; e < E_NUM; e++) {
    for (int off = 32; off > 0; off >>= 1) {
      accR[e] += __shfl_down(accR[e], off, 64);
      accN[e] += __shfl_down(accN[e], off, 64);
    }
  }
  __shared__ float red[4][2 * E_NUM];
  int lane = tid & 63, wave = tid >> 6;
  if (lane == 0) {
#pragma unroll
    for (int e = 0; e < E_NUM; e++) { red[wave][e] = accR[e]; red[wave][E_NUM + e] = accN[e]; }
  }
  __syncthreads();
  if (tid == 0) {
    float ns[E_NUM];
#pragma unroll
    for (int e = 0; e < E_NUM; e++) {
      float lg = red[0][e] + red[1][e] + red[2][e] + red[3][e];
      float nl = red[0][E_NUM + e] + red[1][E_NUM + e] + red[2][E_NUM + e] + red[3][E_NUM + e];
      float sp = fmaxf(nl, 0.f) + log1pf(expf(-fabsf(nl)));
      ns[e] = lg + noise[(size_t)t * E_NUM + e] * sp;
    }
    int i1 = 0; float m1 = ns[0];
    int i2 = -1; float m2 = -INFINITY;
#pragma unroll
    for (int e = 1; e < E_NUM; e++) {
      float v = ns[e];
      if (v > m1) { m2 = m1; i2 = i1; m1 = v; i1 = e; }
      else if (v > m2) { m2 = v; i2 = e; }
    }
    float e2 = expf(m2 - m1);
    float s = 1.f + e2;
    gate_out[t] = make_float2(1.f / s, e2 / s);
    idx_out[t] = make_int2(i1, i2);
  }
}

// ---------------------------------------------------------------------------
// Capacity scan (validated) + per-expert kept count
// ---------------------------------------------------------------------------
__global__ __launch_bounds__(256) void scan_kernel(
    const int2* __restrict__ idx, const float2* __restrict__ gates,
    int* __restrict__ s2t, float* __restrict__ gslot, int* __restrict__ counts,
    int N, int cap)
{
  int e = blockIdx.x;
  int tid = threadIdx.x;
  for (int s = tid; s < cap; s += 256) { s2t[(size_t)e * cap + s] = N; gslot[(size_t)e * cap + s] = 0.f; }
  __syncthreads();
  __shared__ int wtot[4];
  int lane = tid & 63, wave = tid >> 6;
  int running = 0;
  for (int base = 0; base < N; base += 256) {
    int t = base + tid;
    int2 ix = idx[t];
    bool flag = (ix.x == e) || (ix.y == e);
    unsigned long long m = __ballot(flag);
    int rank = __popcll(m & ((1ull << lane) - 1ull));
    if (lane == 0) wtot[wave] = __popcll(m);
    __syncthreads();
    int woff = 0;
    for (int w = 0; w < wave; w++) woff += wtot[w];
    int slot = running + woff + rank;
    if (flag && slot < cap) {
      s2t[(size_t)e * cap + slot] = t;
      gslot[(size_t)e * cap + slot] = (ix.x == e) ? gates[t].x : gates[t].y;
    }
    running += wtot[0] + wtot[1] + wtot[2] + wtot[3];
    __syncthreads();
  }
  if (tid == 0) counts[e] = min(running, cap);
}

// ---------------------------------------------------------------------------
// f32 -> bf16, 8 elems/thread
// ---------------------------------------------------------------------------
__global__ __launch_bounds__(256) void convert_x_kernel(
    const float* __restrict__ src, short* __restrict__ dst, int n8)
{
  int i = blockIdx.x * 256 + threadIdx.x;
  if (i >= n8) return;
  const float4* s = (const float4*)src + (size_t)i * 2;
  float4 a = s[0], b = s[1];
  union { unsigned short us[8]; uint4 v; } o;
  o.us[0] = f2bf(a.x); o.us[1] = f2bf(a.y); o.us[2] = f2bf(a.z); o.us[3] = f2bf(a.w);
  o.us[4] = f2bf(b.x); o.us[5] = f2bf(b.y); o.us[6] = f2bf(b.z); o.us[7] = f2bf(b.w);
  ((uint4*)dst)[i] = o.v;
}

// ---------------------------------------------------------------------------
// f32 [R][Cc] -> bf16 [Cc][R]  (validated)
// ---------------------------------------------------------------------------
__global__ __launch_bounds__(256) void transpose_convert_kernel(
    const float* __restrict__ src, short* __restrict__ dst,
    int R, int Cc)
{
  src += (size_t)blockIdx.z * R * Cc;
  dst += (size_t)blockIdx.z * (size_t)R * Cc;
  __shared__ float tile[64][65];
  int c0 = blockIdx.x * 64, r0 = blockIdx.y * 64;
  int tid = threadIdx.x;
  int tr = tid >> 4, tc = (tid & 15) * 4;
#pragma unroll
  for (int p = 0; p < 4; p++) {
    int r = p * 16 + tr;
    float4 v = *(const float4*)(src + (size_t)(r0 + r) * Cc + c0 + tc);
    tile[r][tc] = v.x; tile[r][tc + 1] = v.y; tile[r][tc + 2] = v.z; tile[r][tc + 3] = v.w;
  }
  __syncthreads();
#pragma unroll
  for (int p = 0; p < 4; p++) {
    int c = p * 16 + tr;
    union { unsigned short us[4]; ushort4 v; } o;
#pragma unroll
    for (int j = 0; j < 4; j++) o.us[j] = f2bf(tile[tc + j][c]);
    *(ushort4*)(dst + (size_t)(c0 + c) * R + r0 + tc) = o.v;
  }
}

// ---------------------------------------------------------------------------
// Pipelined MFMA GEMM core: BM=BN=256, BK=32, 8 waves (2Mx4N), 512 thr.
// 4 LDS tile-buffers (128 KiB), prefetch depth 3, counted vmcnt(8) at ONE raw
// s_barrier per K-tile (no drain-to-0 in steady state). LDS tile layout
// [kb=4][256 rows][8] bf16 (lane-linear for global_load_lds; 0-conflict b128
// reads, validated round 2).
// MODE 0 (mlp1): A = xbf gathered via s2t, B = W1t [H][C], epilogue silu->bf16 h
// MODE 1 (mlp2): A = h [cap][H] (K-chunk kc), B = W2t [C][H], epilogue
//                gate * atomicAdd into out (split-K over 4 chunks of 1024)
// ---------------------------------------------------------------------------
#define TILE_SH 8192      // shorts per tile buffer: 4*256*8

template<int MODE>
__global__ __launch_bounds__(512, 2) void gemm_moe(
    const short* __restrict__ Abase, const short* __restrict__ Wt,
    const int* __restrict__ s2t, const float* __restrict__ gslot,
    const int* __restrict__ counts, void* __restrict__ outp,
    int cap, int N, int rows)
{
  __shared__ short As[4 * TILE_SH];
  __shared__ short Bs[4 * TILE_SH];

  // bijective XCD swizzle (grid is multiple of 8)
  int nwg = gridDim.x;
  int cpx = nwg >> 3;
  int flat = blockIdx.x;
  int swz = (flat & 7) * cpx + (flat >> 3);

  int row, col, e, kc;
  if (MODE == 0) {
    row = swz % rows; int tmp = swz / rows;
    col = tmp & 15; e = tmp >> 4; kc = 0;
  } else {
    row = swz % rows; int tmp = swz / rows;
    col = tmp & 3; tmp >>= 2;
    kc = tmp & 3; e = tmp >> 2;
  }
  int cnt = counts[e];
  int row0 = row * 256;
  if (row0 >= cnt) return;          // whole block is pad slots
  int col0 = col * 256;

  int tid = threadIdx.x;
  int w = tid >> 6, l = tid & 63;
  int wr = w >> 2, wc = w & 3;
  int srow = (w & 3) * 64 + l;      // staged row within tile (A-row / B-col)
  int ko0 = (w >> 2) * 8;           // k offset for stage instr j=0 (kb = w>>2)
  int ko1 = (2 + (w >> 2)) * 8;     // j=1 (kb = 2 + (w>>2))
  int ld0 = (w * 64 + l) * 8;       // LDS dest (shorts) j=0
  int ld1 = (512 + w * 64 + l) * 8; // j=1

  const short* gA;
  const short* gB;
  if (MODE == 0) {
    int tok = s2t[(size_t)e * cap + row0 + srow];
    if (tok >= N) tok = N - 1;      // pad slot: harmless gather (rows unused)
    gA = Abase + (size_t)tok * C_DIM;
    gB = Wt + (size_t)e * (C_DIM * H_DIM) + (size_t)(col0 + srow) * C_DIM;
  } else {
    gA = Abase + ((size_t)e * cap + row0 + srow) * H_DIM + kc * 1024;
    gB = Wt + (size_t)e * (C_DIM * H_DIM) + (size_t)(col0 + srow) * H_DIM + kc * 1024;
  }
  const int KT = 32;                // 1024 / 32 both modes

  // fragment read bases (shorts within a tile buffer)
  int aBase = ((l >> 4) * 256 + wr * 128 + (l & 15)) * 8;
  int bBase = ((l >> 4) * 256 + wc * 64 + (l & 15)) * 8;

  f32x4 acc[8][4];
#pragma unroll
  for (int m = 0; m < 8; m++)
#pragma unroll
    for (int n = 0; n < 4; n++) acc[m][n] = 0.f;

  // prologue: stage tiles 0,1,2
#pragma unroll
  for (int t = 0; t < 3; ++t) {
    int boff = t * TILE_SH;
    gload16(gA + t * 32 + ko0, &As[boff + ld0]);
    gload16(gA + t * 32 + ko1, &As[boff + ld1]);
    gload16(gB + t * 32 + ko0, &Bs[boff + ld0]);
    gload16(gB + t * 32 + ko1, &Bs[boff + ld1]);
  }

#pragma unroll 1
  for (int t = 0; t < KT; ++t) {
    // boundary: tile t's loads retired (in-order vmcnt), then cross-wave sync.
    if (t < KT - 2)       asm volatile("s_waitcnt vmcnt(8)" ::: "memory");
    else if (t == KT - 2) asm volatile("s_waitcnt vmcnt(4)" ::: "memory");
    else                  asm volatile("s_waitcnt vmcnt(0)" ::: "memory");
    __builtin_amdgcn_s_barrier();
    __builtin_amdgcn_sched_barrier(0);

    int bufc = (t & 3) * TILE_SH;
    int tp = t + 3;
    int bufp = (tp & 3) * TILE_SH;
    bool st = tp < KT;

    // ---- phase 0: stage A(t+3); compute m0..3 x n0..3 ----
    if (st) {
      gload16(gA + tp * 32 + ko0, &As[bufp + ld0]);
      gload16(gA + tp * 32 + ko1, &As[bufp + ld1]);
    }
    bf16x8 bfr[4], afr[4];
#pragma unroll
    for (int n = 0; n < 4; n++) bfr[n] = *(const bf16x8*)&Bs[bufc + bBase + n * 128];
#pragma unroll
    for (int m = 0; m < 4; m++) afr[m] = *(const bf16x8*)&As[bufc + aBase + m * 128];
    __builtin_amdgcn_s_setprio(1);
#pragma unroll
    for (int m = 0; m < 4; m++)
#pragma unroll
      for (int n = 0; n < 4; n++)
        acc[m][n] = __builtin_amdgcn_mfma_f32_16x16x32_bf16(afr[m], bfr[n], acc[m][n], 0, 0, 0);
    __builtin_amdgcn_s_setprio(0);

    // ---- phase 1: stage B(t+3); compute m4..7 x n0..3 ----
    if (st) {
      gload16(gB + tp * 32 + ko0, &Bs[bufp + ld0]);
      gload16(gB + tp * 32 + ko1, &Bs[bufp + ld1]);
    }
#pragma unroll
    for (int m = 0; m < 4; m++) afr[m] = *(const bf16x8*)&As[bufc + aBase + (m + 4) * 128];
    __builtin_amdgcn_s_setprio(1);
#pragma unroll
    for (int m = 0; m < 4; m++)
#pragma unroll
      for (int n = 0; n < 4; n++)
        acc[m + 4][n] = __builtin_amdgcn_mfma_f32_16x16x32_bf16(afr[m], bfr[n], acc[m + 4][n], 0, 0, 0);
    __builtin_amdgcn_s_setprio(0);
  }

  // ---- epilogue ----
  int orow = row0 + wr * 128 + (l >> 4) * 4;
  int ocol = col0 + wc * 64 + (l & 15);
  if (MODE == 0) {
    short* hE = (short*)outp + (size_t)e * cap * H_DIM;
#pragma unroll
    for (int m = 0; m < 8; m++)
#pragma unroll
      for (int r = 0; r < 4; r++) {
        size_t rb = (size_t)(orow + m * 16 + r) * H_DIM + ocol;
#pragma unroll
        for (int n = 0; n < 4; n++) {
          float v = acc[m][n][r];
          hE[rb + n * 16] = (short)f2bf(v / (1.f + expf(-v)));
        }
      }
  } else {
    float* out = (float*)outp;
#pragma unroll
    for (int m = 0; m < 8; m++)
#pragma unroll
      for (int r = 0; r < 4; r++) {
        int slot = row0 + wr * 128 + m * 16 + (l >> 4) * 4 + r;
        int tok = s2t[(size_t)e * cap + slot];
        if (tok < N) {
          float g = gslot[(size_t)e * cap + slot];
          float* op = out + (size_t)tok * C_DIM + ocol;
#pragma unroll
          for (int n = 0; n < 4; n++)
            atomicAdd(op + n * 16, g * acc[m][n][r]);
        }
      }
  }
}

extern "C" void kernel_launch(void* const* d_in, const int* in_sizes, int n_in,
                              void* d_out, int out_size, void* d_ws, size_t ws_size,
                              hipStream_t stream)
{
  const float* x     = (const float*)d_in[0];
  const float* noise = (const float*)d_in[1];
  const float* Wr    = (const float*)d_in[2];
  const float* Wn    = (const float*)d_in[3];
  const float* W1    = (const float*)d_in[4];
  const float* W2    = (const float*)d_in[5];
  float* out = (float*)d_out;

  int N = in_sizes[0] / C_DIM;                        // 8192
  int cap = (int)((double)N * 2.0 / E_NUM * 1.25);    // 2560
  int rows = cap / 256;                               // 10

  size_t off = 0;
  auto alloc = [&](size_t bytes) -> char* {
    char* r = (char*)d_ws + off;
    off += (bytes + 255) & ~(size_t)255;
    return r;
  };
  int2*   idx    = (int2*)alloc((size_t)N * sizeof(int2));
  float2* gates  = (float2*)alloc((size_t)N * sizeof(float2));
  int*    s2t    = (int*)alloc((size_t)E_NUM * cap * sizeof(int));
  float*  gslot  = (float*)alloc((size_t)E_NUM * cap * sizeof(float));
  int*    counts = (int*)alloc(E_NUM * sizeof(int));
  short*  xbf    = (short*)alloc((size_t)N * C_DIM * sizeof(short));
  short*  W1t    = (short*)alloc((size_t)E_NUM * C_DIM * H_DIM * sizeof(short));
  short*  W2t    = (short*)alloc((size_t)E_NUM * C_DIM * H_DIM * sizeof(short));
  short*  h      = (short*)alloc((size_t)E_NUM * cap * H_DIM * sizeof(short));
  (void)ws_size; // ~312 MB needed; harness workspace verified >= this in R2

  hipMemsetAsync(d_out, 0, (size_t)out_size * sizeof(float), stream);
  router_kernel<<<N, 256, 0, stream>>>(x, noise, Wr, Wn, idx, gates, N);
  scan_kernel<<<E_NUM, 256, 0, stream>>>(idx, gates, s2t, gslot, counts, N, cap);
  convert_x_kernel<<<(N * C_DIM / 8 + 255) / 256, 256, 0, stream>>>(x, xbf, N * C_DIM / 8);
  transpose_convert_kernel<<<dim3(H_DIM / 64, C_DIM / 64, E_NUM), 256, 0, stream>>>(
      W1, W1t, C_DIM, H_DIM);
  transpose_convert_kernel<<<dim3(C_DIM / 64, H_DIM / 64, E_NUM), 256, 0, stream>>>(
      W2, W2t, H_DIM, C_DIM);

  // mlp1: grid = 16 cols * rows * 8 experts = 1280
  gemm_moe<0><<<dim3(16 * rows * E_NUM), 512, 0, stream>>>(
      xbf, W1t, s2t, gslot, counts, h, cap, N, rows);
  // mlp2: grid = 4 cols * rows * 4 kchunks * 8 experts = 1280
  gemm_moe<1><<<dim3(4 * rows * 4 * E_NUM), 512, 0, stream>>>(
      h, W2t, s2t, gslot, counts, out, cap, N, rows);
}

// Round 4
// 784.290 us; speedup vs baseline: 5.4559x; 1.1038x over previous
//
#include <hip/hip_runtime.h>
#include <hip/hip_bf16.h>
#include <math.h>

#define C_DIM 1024
#define H_DIM 4096
#define E_NUM 8

typedef __bf16 bf16x8 __attribute__((ext_vector_type(8)));
typedef float f32x4 __attribute__((ext_vector_type(4)));
typedef unsigned u32x4 __attribute__((ext_vector_type(4)));

__device__ __forceinline__ unsigned short f2bf(float f) {
  union { float f; unsigned u; } v; v.f = f;
  unsigned r = v.u + 0x7FFFu + ((v.u >> 16) & 1u);   // round-to-nearest-even
  return (unsigned short)(r >> 16);
}

__device__ __forceinline__ void gload16(const short* g, short* l) {
  __builtin_amdgcn_global_load_lds(
      (const __attribute__((address_space(1))) unsigned int*)g,
      (__attribute__((address_space(3))) unsigned int*)l, 16, 0, 0);
}

__device__ __forceinline__ f32x4 mfma16(u32x4 a, u32x4 b, f32x4 c) {
  return __builtin_amdgcn_mfma_f32_16x16x32_bf16(
      __builtin_bit_cast(bf16x8, a), __builtin_bit_cast(bf16x8, b), c, 0, 0, 0);
}

// inline-asm ds_read_b128: invisible to the compiler's LDS-DMA hazard pass, so
// our counted vmcnt governs (round-3 collapse = compiler vmcnt(0) drains).
#define DSR(v, a, imm) asm volatile("ds_read_b128 %0, %1 offset:" #imm : "=v"(v) : "v"(a))
#define BAR __builtin_amdgcn_s_barrier()
#define LGKM0 { asm volatile("s_waitcnt lgkmcnt(0)" ::: "memory"); __builtin_amdgcn_sched_barrier(0); }
#define VMW(n) asm volatile("s_waitcnt vmcnt(" #n ")" ::: "memory")
#define SP1 __builtin_amdgcn_s_setprio(1)
#define SP0 __builtin_amdgcn_s_setprio(0)
#define STG(p, d) { gload16((p), (d)); gload16((p) + 32, (d) + 4096); }
#define LDS_U32(p) ((unsigned)(size_t)(__attribute__((address_space(3))) short*)(p))

// ---------------------------------------------------------------------------
// Router (validated rounds 1-3)
// ---------------------------------------------------------------------------
__global__ __launch_bounds__(256) void router_kernel(
    const float* __restrict__ x, const float* __restrict__ noise,
    const float* __restrict__ Wr, const float* __restrict__ Wn,
    int2* __restrict__ idx_out, float2* __restrict__ gate_out, int N)
{
  int t = blockIdx.x;
  int tid = threadIdx.x;
  const float* xrow = x + (size_t)t * C_DIM;
  float accR[E_NUM], accN[E_NUM];
#pragma unroll
  for (int e = 0; e < E_NUM; e++) { accR[e] = 0.f; accN[e] = 0.f; }
  for (int c = tid; c < C_DIM; c += 256) {
    float xv = xrow[c];
    const float* wr = Wr + (size_t)c * E_NUM;
    const float* wn = Wn + (size_t)c * E_NUM;
#pragma unroll
    for (int e = 0; e < E_NUM; e++) {
      accR[e] = fmaf(xv, wr[e], accR[e]);
      accN[e] = fmaf(xv, wn[e], accN[e]);
    }
  }
#pragma unroll
  for (int e = 0; e < E_NUM; e++) {
    for (int off = 32; off > 0; off >>= 1) {
      accR[e] += __shfl_down(accR[e], off, 64);
      accN[e] += __shfl_down(accN[e], off, 64);
    }
  }
  __shared__ float red[4][2 * E_NUM];
  int lane = tid & 63, wave = tid >> 6;
  if (lane == 0) {
#pragma unroll
    for (int e = 0; e < E_NUM; e++) { red[wave][e] = accR[e]; red[wave][E_NUM + e] = accN[e]; }
  }
  __syncthreads();
  if (tid == 0) {
    float ns[E_NUM];
#pragma unroll
    for (int e = 0; e < E_NUM; e++) {
      float lg = red[0][e] + red[1][e] + red[2][e] + red[3][e];
      float nl = red[0][E_NUM + e] + red[1][E_NUM + e] + red[2][E_NUM + e] + red[3][E_NUM + e];
      float sp = fmaxf(nl, 0.f) + log1pf(expf(-fabsf(nl)));
      ns[e] = lg + noise[(size_t)t * E_NUM + e] * sp;
    }
    int i1 = 0; float m1 = ns[0];
    int i2 = -1; float m2 = -INFINITY;
#pragma unroll
    for (int e = 1; e < E_NUM; e++) {
      float v = ns[e];
      if (v > m1) { m2 = m1; i2 = i1; m1 = v; i1 = e; }
      else if (v > m2) { m2 = v; i2 = e; }
    }
    float e2 = expf(m2 - m1);
    float s = 1.f + e2;
    gate_out[t] = make_float2(1.f / s, e2 / s);
    idx_out[t] = make_int2(i1, i2);
  }
}

// ---------------------------------------------------------------------------
// Capacity scan (validated) + per-expert kept count
// ---------------------------------------------------------------------------
__global__ __launch_bounds__(256) void scan_kernel(
    const int2* __restrict__ idx, const float2* __restrict__ gates,
    int* __restrict__ s2t, float* __restrict__ gslot, int* __restrict__ counts,
    int N, int cap)
{
  int e = blockIdx.x;
  int tid = threadIdx.x;
  for (int s = tid; s < cap; s += 256) { s2t[(size_t)e * cap + s] = N; gslot[(size_t)e * cap + s] = 0.f; }
  __syncthreads();
  __shared__ int wtot[4];
  int lane = tid & 63, wave = tid >> 6;
  int running = 0;
  for (int base = 0; base < N; base += 256) {
    int t = base + tid;
    int2 ix = idx[t];
    bool flag = (ix.x == e) || (ix.y == e);
    unsigned long long m = __ballot(flag);
    int rank = __popcll(m & ((1ull << lane) - 1ull));
    if (lane == 0) wtot[wave] = __popcll(m);
    __syncthreads();
    int woff = 0;
    for (int w = 0; w < wave; w++) woff += wtot[w];
    int slot = running + woff + rank;
    if (flag && slot < cap) {
      s2t[(size_t)e * cap + slot] = t;
      gslot[(size_t)e * cap + slot] = (ix.x == e) ? gates[t].x : gates[t].y;
    }
    running += wtot[0] + wtot[1] + wtot[2] + wtot[3];
    __syncthreads();
  }
  if (tid == 0) counts[e] = min(running, cap);
}

// ---------------------------------------------------------------------------
// f32 -> bf16, 8 elems/thread
// ---------------------------------------------------------------------------
__global__ __launch_bounds__(256) void convert_x_kernel(
    const float* __restrict__ src, short* __restrict__ dst, int n8)
{
  int i = blockIdx.x * 256 + threadIdx.x;
  if (i >= n8) return;
  const float4* s = (const float4*)src + (size_t)i * 2;
  float4 a = s[0], b = s[1];
  union { unsigned short us[8]; uint4 v; } o;
  o.us[0] = f2bf(a.x); o.us[1] = f2bf(a.y); o.us[2] = f2bf(a.z); o.us[3] = f2bf(a.w);
  o.us[4] = f2bf(b.x); o.us[5] = f2bf(b.y); o.us[6] = f2bf(b.z); o.us[7] = f2bf(b.w);
  ((uint4*)dst)[i] = o.v;
}

// ---------------------------------------------------------------------------
// f32 [R][Cc] -> bf16 [Cc][R]  (validated)
// ---------------------------------------------------------------------------
__global__ __launch_bounds__(256) void transpose_convert_kernel(
    const float* __restrict__ src, short* __restrict__ dst,
    int R, int Cc)
{
  src += (size_t)blockIdx.z * R * Cc;
  dst += (size_t)blockIdx.z * (size_t)R * Cc;
  __shared__ float tile[64][65];
  int c0 = blockIdx.x * 64, r0 = blockIdx.y * 64;
  int tid = threadIdx.x;
  int tr = tid >> 4, tc = (tid & 15) * 4;
#pragma unroll
  for (int p = 0; p < 4; p++) {
    int r = p * 16 + tr;
    float4 v = *(const float4*)(src + (size_t)(r0 + r) * Cc + c0 + tc);
    tile[r][tc] = v.x; tile[r][tc + 1] = v.y; tile[r][tc + 2] = v.z; tile[r][tc + 3] = v.w;
  }
  __syncthreads();
#pragma unroll
  for (int p = 0; p < 4; p++) {
    int c = p * 16 + tr;
    union { unsigned short us[4]; ushort4 v; } o;
#pragma unroll
    for (int j = 0; j < 4; j++) o.us[j] = f2bf(tile[tc + j][c]);
    *(ushort4*)(dst + (size_t)(c0 + c) * R + r0 + tc) = o.v;
  }
}

// ---------------------------------------------------------------------------
// 8-phase MFMA GEMM (m201 template, adapted): BM=BN=256, BK=64, 8 waves
// (2M x 4N), 512 thr, per-wave 128x64 output. LDS [buf2][half2][kb8][row128][8]
// bf16 per operand = 128 KiB total (conflict-free; measured 0 conflicts).
// 2 K-tiles/iter, 8 phases: each = {asm ds_reads | 1 half-tile stage | barrier |
// lgkmcnt(0)+sched_barrier | setprio(1) 16 MFMA setprio(0) | barrier}.
// vmcnt(4) only at phase 4/8 boundaries (drain-0 only on last iter ph3).
// MODE 0 (mlp1): A = xbf via s2t gather, B = W1t [H][C]; silu->bf16 h.
// MODE 1 (mlp2): A = h [cap][H] chunk kc, B = W2t [C][H]; gate*atomicAdd.
// ---------------------------------------------------------------------------
template<int MODE>
__global__ __launch_bounds__(512, 2) void gemm_moe(
    const short* __restrict__ Abase, const short* __restrict__ Wt,
    const int* __restrict__ s2t, const float* __restrict__ gslot,
    const int* __restrict__ counts, void* __restrict__ outp,
    int cap, int N, int rows)
{
  __shared__ short As[32768];   // [buf][half][kb][row][8]: buf*16384+half*8192+kb*1024+row*8 shorts
  __shared__ short Bs[32768];

  // bijective XCD swizzle (grid multiple of 8)
  int nwg = gridDim.x;
  int cpx = nwg >> 3;
  int flat = blockIdx.x;
  int swz = (flat & 7) * cpx + (flat >> 3);

  int row, col, e, kc;
  if (MODE == 0) {
    row = swz % rows; int tmp = swz / rows;
    col = tmp & 15; e = tmp >> 4; kc = 0;
  } else {
    row = swz % rows; int tmp = swz / rows;
    col = tmp & 3; tmp >>= 2;
    kc = tmp & 3; e = tmp >> 2;
  }
  int cnt = counts[e];
  int row0 = row * 256;
  if (row0 >= cnt) return;          // whole block is pad slots
  int col0 = col * 256;

  int tid = threadIdx.x;
  int w = tid >> 6, l = tid & 63;
  int wr = w >> 2, wc = w & 3;      // 2M x 4N wave grid

  // staging constants: thread covers (rowT, kbT) and (rowT, kbT+4)
  int rowT = tid & 127;
  int kbT = tid >> 7;               // 0..3
  int kb8 = kbT * 8;                // global k offset of sweep 0
  int dOff = kbT * 1024 + rowT * 8; // LDS shorts offset within a half

  // global source pointers (shorts), one per operand-half
  const short *pA0, *pA1, *pB0, *pB1;
  if (MODE == 0) {
    int tok0 = min(s2t[(size_t)e * cap + row0 + rowT], N - 1);
    int tok1 = min(s2t[(size_t)e * cap + row0 + 128 + rowT], N - 1);
    pA0 = Abase + (size_t)tok0 * C_DIM;
    pA1 = Abase + (size_t)tok1 * C_DIM;
    pB0 = Wt + (size_t)e * (C_DIM * H_DIM) + (size_t)(col0 + rowT) * C_DIM;
    pB1 = Wt + (size_t)e * (C_DIM * H_DIM) + (size_t)(col0 + 128 + rowT) * C_DIM;
  } else {
    pA0 = Abase + ((size_t)e * cap + row0 + rowT) * H_DIM + kc * 1024;
    pA1 = Abase + ((size_t)e * cap + row0 + 128 + rowT) * H_DIM + kc * 1024;
    pB0 = Wt + (size_t)e * (C_DIM * H_DIM) + (size_t)(col0 + rowT) * H_DIM + kc * 1024;
    pB1 = Wt + (size_t)e * (C_DIM * H_DIM) + (size_t)(col0 + 128 + rowT) * H_DIM + kc * 1024;
  }

  // fragment ds_read byte bases (buf0); +32768 for buf1; +1024 for A mh1
  unsigned aB0 = LDS_U32(As) + (unsigned)(wr * 16384 + (l >> 4) * 2048 + (l & 15) * 16);
  unsigned bB0 = LDS_U32(Bs) + (unsigned)((wc >> 1) * 16384 + (l >> 4) * 2048 + ((wc & 1) * 64 + (l & 15)) * 16);
  unsigned aB1 = aB0 + 32768, bB1 = bB0 + 32768;

  f32x4 acc[8][4];
#pragma unroll
  for (int m = 0; m < 8; m++)
#pragma unroll
    for (int n = 0; n < 4; n++) acc[m][n] = 0.f;

  u32x4 aF0[4], aF1[4];             // A frags [kk][mm] for current mh
  u32x4 bA[2], bB[2], bC[2], bD[2]; // B frags: nh0 kk0/kk1, nh1 kk0/kk1

#define RD_A(aa) { DSR(aF0[0],(aa),0); DSR(aF0[1],(aa),256); DSR(aF0[2],(aa),512); DSR(aF0[3],(aa),768); \
                   DSR(aF1[0],(aa),8192); DSR(aF1[1],(aa),8448); DSR(aF1[2],(aa),8704); DSR(aF1[3],(aa),8960); }
#define RD_BN0(bb) { DSR(bA[0],(bb),0); DSR(bA[1],(bb),256); DSR(bB[0],(bb),8192); DSR(bB[1],(bb),8448); }
#define RD_BN1(bb) { DSR(bC[0],(bb),512); DSR(bC[1],(bb),768); DSR(bD[0],(bb),8704); DSR(bD[1],(bb),8960); }
#define QUAD(MH, NH, F0, F1) { SP1; \
  _Pragma("unroll") for (int mm = 0; mm < 4; mm++) \
    _Pragma("unroll") for (int nn = 0; nn < 2; nn++) { \
      acc[(MH)*4+mm][(NH)*2+nn] = mfma16(aF0[mm], F0[nn], acc[(MH)*4+mm][(NH)*2+nn]); \
      acc[(MH)*4+mm][(NH)*2+nn] = mfma16(aF1[mm], F1[nn], acc[(MH)*4+mm][(NH)*2+nn]); \
    } SP0; }

  // prologue: tile0 -> buf0 (all 4 halves), tile1 -> buf1 (Bh0, Ah0)
  STG(pB0 + kb8,      Bs + dOff);           // t0 Bh0
  STG(pA0 + kb8,      As + dOff);           // t0 Ah0
  STG(pA1 + kb8,      As + 8192 + dOff);    // t0 Ah1
  STG(pB1 + kb8,      Bs + 8192 + dOff);    // t0 Bh1
  STG(pB0 + 64 + kb8, Bs + 16384 + dOff);   // t1 Bh0
  STG(pA0 + 64 + kb8, As + 16384 + dOff);   // t1 Ah0
  VMW(4); BAR;

  const int NIT = 8;                // 16 K-tiles of 64 = K 1024
#pragma unroll 1
  for (int i = 0; i < NIT; ++i) {
    bool lastI = (i == NIT - 1);
    int t1k = (2 * i + 1) * 64, t2k = (2 * i + 2) * 64, t3k = (2 * i + 3) * 64;

    // ---- ph0: read buf0 A(mh0)+B(nh0); stage buf1 Ah1 (tile 2i+1) ----
    RD_A(aB0); RD_BN0(bB0);
    STG(pA1 + t1k + kb8, As + 16384 + 8192 + dOff);
    BAR; LGKM0;
    QUAD(0, 0, bA, bB);
    BAR;
    // ---- ph1: read buf0 B(nh1); stage buf1 Bh1 (tile 2i+1) ----
    RD_BN1(bB0);
    STG(pB1 + t1k + kb8, Bs + 16384 + 8192 + dOff);
    BAR; LGKM0;
    QUAD(0, 1, bC, bD);
    BAR;
    // ---- ph2: read buf0 A(mh1); stage buf0 Bh0 (tile 2i+2) ----
    RD_A(aB0 + 1024);
    if (!lastI) STG(pB0 + t2k + kb8, Bs + dOff);
    BAR; LGKM0;
    QUAD(1, 1, bC, bD);
    BAR;
    // ---- ph3: stage buf0 Ah0 (tile 2i+2); vmcnt boundary ----
    if (!lastI) STG(pA0 + t2k + kb8, As + dOff);
    BAR;
    QUAD(1, 0, bA, bB);
    if (lastI) { VMW(0); } else { VMW(4); }
    BAR;
    // ---- ph4: read buf1 A(mh0)+B(nh0); stage buf0 Ah1 (tile 2i+2) ----
    RD_A(aB1); RD_BN0(bB1);
    if (!lastI) STG(pA1 + t2k + kb8, As + 8192 + dOff);
    BAR; LGKM0;
    QUAD(0, 0, bA, bB);
    BAR;
    // ---- ph5: read buf1 B(nh1); stage buf0 Bh1 (tile 2i+2) ----
    RD_BN1(bB1);
    if (!lastI) STG(pB1 + t2k + kb8, Bs + 8192 + dOff);
    BAR; LGKM0;
    QUAD(0, 1, bC, bD);
    BAR;
    // ---- ph6: read buf1 A(mh1); stage buf1 Bh0 (tile 2i+3) ----
    RD_A(aB1 + 1024);
    if (!lastI) STG(pB0 + t3k + kb8, Bs + 16384 + dOff);
    BAR; LGKM0;
    QUAD(1, 1, bC, bD);
    BAR;
    // ---- ph7: stage buf1 Ah0 (tile 2i+3); vmcnt boundary ----
    if (!lastI) STG(pA0 + t3k + kb8, As + 16384 + dOff);
    BAR;
    QUAD(1, 0, bA, bB);
    VMW(4);
    BAR;
  }

  // ---- epilogue ----
  int orow = row0 + wr * 128 + (l >> 4) * 4;
  int ocol = col0 + wc * 64 + (l & 15);
  if (MODE == 0) {
    short* hE = (short*)outp + (size_t)e * cap * H_DIM;
#pragma unroll
    for (int m = 0; m < 8; m++)
#pragma unroll
      for (int r = 0; r < 4; r++) {
        size_t rb = (size_t)(orow + m * 16 + r) * H_DIM + ocol;
#pragma unroll
        for (int n = 0; n < 4; n++) {
          float v = acc[m][n][r];
          hE[rb + n * 16] = (short)f2bf(v / (1.f + expf(-v)));
        }
      }
  } else {
    float* out = (float*)outp;
#pragma unroll
    for (int m = 0; m < 8; m++)
#pragma unroll
      for (int r = 0; r < 4; r++) {
        int slot = row0 + wr * 128 + m * 16 + (l >> 4) * 4 + r;
        int tok = s2t[(size_t)e * cap + slot];
        if (tok < N) {
          float g = gslot[(size_t)e * cap + slot];
          float* op = out + (size_t)tok * C_DIM + ocol;
#pragma unroll
          for (int n = 0; n < 4; n++)
            atomicAdd(op + n * 16, g * acc[m][n][r]);
        }
      }
  }
#undef RD_A
#undef RD_BN0
#undef RD_BN1
#undef QUAD
}

extern "C" void kernel_launch(void* const* d_in, const int* in_sizes, int n_in,
                              void* d_out, int out_size, void* d_ws, size_t ws_size,
                              hipStream_t stream)
{
  const float* x     = (const float*)d_in[0];
  const float* noise = (const float*)d_in[1];
  const float* Wr    = (const float*)d_in[2];
  const float* Wn    = (const float*)d_in[3];
  const float* W1    = (const float*)d_in[4];
  const float* W2    = (const float*)d_in[5];
  float* out = (float*)d_out;

  int N = in_sizes[0] / C_DIM;                        // 8192
  int cap = (int)((double)N * 2.0 / E_NUM * 1.25);    // 2560
  int rows = cap / 256;                               // 10

  size_t off = 0;
  auto alloc = [&](size_t bytes) -> char* {
    char* r = (char*)d_ws + off;
    off += (bytes + 255) & ~(size_t)255;
    return r;
  };
  int2*   idx    = (int2*)alloc((size_t)N * sizeof(int2));
  float2* gates  = (float2*)alloc((size_t)N * sizeof(float2));
  int*    s2t    = (int*)alloc((size_t)E_NUM * cap * sizeof(int));
  float*  gslot  = (float*)alloc((size_t)E_NUM * cap * sizeof(float));
  int*    counts = (int*)alloc(E_NUM * sizeof(int));
  short*  xbf    = (short*)alloc((size_t)N * C_DIM * sizeof(short));
  short*  W1t    = (short*)alloc((size_t)E_NUM * C_DIM * H_DIM * sizeof(short));
  short*  W2t    = (short*)alloc((size_t)E_NUM * C_DIM * H_DIM * sizeof(short));
  short*  h      = (short*)alloc((size_t)E_NUM * cap * H_DIM * sizeof(short));
  (void)ws_size;

  hipMemsetAsync(d_out, 0, (size_t)out_size * sizeof(float), stream);
  router_kernel<<<N, 256, 0, stream>>>(x, noise, Wr, Wn, idx, gates, N);
  scan_kernel<<<E_NUM, 256, 0, stream>>>(idx, gates, s2t, gslot, counts, N, cap);
  convert_x_kernel<<<(N * C_DIM / 8 + 255) / 256, 256, 0, stream>>>(x, xbf, N * C_DIM / 8);
  transpose_convert_kernel<<<dim3(H_DIM / 64, C_DIM / 64, E_NUM), 256, 0, stream>>>(
      W1, W1t, C_DIM, H_DIM);
  transpose_convert_kernel<<<dim3(C_DIM / 64, H_DIM / 64, E_NUM), 256, 0, stream>>>(
      W2, W2t, H_DIM, C_DIM);

  // mlp1: 16 cols * 10 rows * 8 experts = 1280 blocks
  gemm_moe<0><<<dim3(16 * rows * E_NUM), 512, 0, stream>>>(
      xbf, W1t, s2t, gslot, counts, h, cap, N, rows);
  // mlp2: 4 cols * 10 rows * 4 kchunks * 8 experts = 1280 blocks
  gemm_moe<1><<<dim3(4 * rows * 4 * E_NUM), 512, 0, stream>>>(
      h, W2t, s2t, gslot, counts, out, cap, N, rows);
}